// Round 2
// baseline (254.167 us; speedup 1.0000x reference)
//
#include <hip/hip_runtime.h>
#include <math.h>

#define S 4096
#define CNUM 128
#define BATCH 4
#define MTOT (BATCH * S)
#define SCLOG2E 0.36067376022224085f   // 0.25 * log2(e): scores in log2 domain
#define EPSLN 1e-5f
#define NSPLIT 8
#define KCH2 64                         // V k-chunk per pipeline stage (16 KB image)

typedef __attribute__((ext_vector_type(8))) short bf16x8;
typedef __attribute__((ext_vector_type(4))) float f32x4;

__device__ __forceinline__ float gelu_exact(float x) {
    return 0.5f * x * (1.0f + erff(x * 0.7071067811865476f));
}

__device__ __forceinline__ unsigned short f2b(float f) {
    union { float f; unsigned int u; } v; v.f = f;
    unsigned int r = (v.u + 0x7FFFu + ((v.u >> 16) & 1u)) >> 16;
    return (unsigned short)r;
}
// cheap round-half-up for positive values (2 ops)
__device__ __forceinline__ unsigned short f2b_ru(float f) {
    return (unsigned short)((__float_as_uint(f) + 0x8000u) >> 16);
}
__device__ __forceinline__ float b2f(unsigned short u) {
    return __uint_as_float((unsigned)u << 16);
}

// async 16B global->LDS (direct DMA, no VGPR round trip)
__device__ __forceinline__ void gl_lds16(const void* g, void* l) {
    __builtin_amdgcn_global_load_lds(
        (__attribute__((address_space(1))) void*)g,
        (__attribute__((address_space(3))) void*)l, 16, 0, 0);
}

// ---------------- transpose [B,C,S] -> [B,S,C]: t fp32 (residual), xlh bf16 (LN1 out) ----------------
__global__ __launch_bounds__(256) void ln1_transpose(
    const float* __restrict__ x, const float* __restrict__ w, const float* __restrict__ bb,
    unsigned short* __restrict__ xlh, float* __restrict__ t)
{
    __shared__ float tile[128][65];
    __shared__ float mu[64], rs[64];
    const int b = blockIdx.y;
    const int s0 = blockIdx.x * 64;
    const float* xb = x + (size_t)b * CNUM * S;
    for (int i = threadIdx.x; i < 128 * 64; i += 256) {
        int c = i >> 6, sl = i & 63;
        tile[c][sl] = xb[(size_t)c * S + s0 + sl];
    }
    __syncthreads();
    if (threadIdx.x < 64) {
        float sum = 0.f, sq = 0.f;
        for (int c = 0; c < 128; ++c) {
            float v = tile[c][threadIdx.x];
            sum += v; sq += v * v;
        }
        float m = sum * (1.f / 128.f);
        float var = sq * (1.f / 128.f) - m * m;
        mu[threadIdx.x] = m;
        rs[threadIdx.x] = rsqrtf(var + EPSLN);
    }
    __syncthreads();
    for (int i = threadIdx.x; i < 128 * 64; i += 256) {
        int c = i & 127, sl = i >> 7;
        float v = tile[c][sl];
        size_t idx = ((size_t)b * S + s0 + sl) * CNUM + c;
        t[idx] = v;
        xlh[idx] = f2b((v - mu[sl]) * rs[sl] * w[c] + bb[c]);
    }
}

// ---------------- weight convert+transpose fp32[K,N] -> bf16[N,K]; biases packed ----------------
__global__ __launch_bounds__(256) void convw(
    const float* __restrict__ wq, const float* __restrict__ wk, const float* __restrict__ wv,
    const float* __restrict__ wo, const float* __restrict__ w1, const float* __restrict__ w2,
    const float* __restrict__ bq, const float* __restrict__ bk, const float* __restrict__ bv,
    unsigned short* __restrict__ wqkvh, unsigned short* __restrict__ woh,
    unsigned short* __restrict__ w1h, unsigned short* __restrict__ w2h,
    float* __restrict__ bqkv)
{
    int a = blockIdx.y;
    int idx = blockIdx.x * 256 + threadIdx.x;
    if (a == 6) {
        if (idx < 128) bqkv[idx] = bq[idx];
        else if (idx < 256) bqkv[idx] = bk[idx - 128];
        else if (idx < 384) bqkv[idx] = bv[idx - 256];
        return;
    }
    const float* src; unsigned short* dst; int Nsh, Ksz;
    switch (a) {
        case 0: src = wq; dst = wqkvh;          Nsh = 7; Ksz = 128; break;
        case 1: src = wk; dst = wqkvh + 16384;  Nsh = 7; Ksz = 128; break;
        case 2: src = wv; dst = wqkvh + 32768;  Nsh = 7; Ksz = 128; break;
        case 3: src = wo; dst = woh;            Nsh = 7; Ksz = 128; break;
        case 4: src = w1; dst = w1h;            Nsh = 8; Ksz = 128; break;
        default: src = w2; dst = w2h;           Nsh = 7; Ksz = 256; break;
    }
    int total = Ksz << Nsh;
    if (idx >= total) return;
    int k = idx >> Nsh, n = idx & ((1 << Nsh) - 1);
    dst[n * Ksz + k] = f2b(src[idx]);
}

// ---------------- MFMA GEMM: C = A[M,KT](bf16) @ Bt[N,KT]^T(bf16) + bias, epilogues ----------------
// epi: 2 = fp32 +res -> C[M,N]
//      6 = gelu -> bf16 C[M,N]
//      7 = QKV combined (z=0,1: bf16 [M,128]; z=2: bf16 V written in pre-swizzled
//          per-64k-chunk LDS-image layout [b][kc][c*64 + ((g^(c&7))*8) + (k&7)])
//      8 = gelu + res -> fp32 out[b][col][s] (fused final transpose)
template<int KT>
__global__ __launch_bounds__(256) void gemm_mfma(
    const unsigned short* __restrict__ A, const unsigned short* __restrict__ Bt,
    const float* __restrict__ bias, const float* __restrict__ res,
    void* __restrict__ Cv, int N, int epi)
{
    constexpr int CH = KT / 8;
    constexpr int CSH = (KT == 128) ? 4 : 5;
    __shared__ unsigned short As[64 * KT];
    __shared__ unsigned short Bs[128 * KT];
    const int bm = blockIdx.y * 64;
    const int bn = blockIdx.x * 128;
    const int z = blockIdx.z;
    const unsigned short* Btz = (epi == 7) ? Bt + z * 16384 : Bt;
    const float* biasz = (epi == 7) ? bias + z * 128 : bias;
    const int tid = threadIdx.x;
    const int w = tid >> 6, l = tid & 63;
    const int rw = (w & 1) * 32, cw = (w >> 1) * 64;

    #pragma unroll
    for (int i = 0; i < (64 * CH) / 256; ++i) {
        int cid = i * 256 + tid;
        int r = cid >> CSH, c = cid & (CH - 1);
        int p = (c & ~15) | ((c ^ r) & 15);
        *(ulonglong2*)(As + r * KT + p * 8) =
            *(const ulonglong2*)(A + (size_t)(bm + r) * KT + c * 8);
    }
    #pragma unroll
    for (int i = 0; i < (128 * CH) / 256; ++i) {
        int cid = i * 256 + tid;
        int r = cid >> CSH, c = cid & (CH - 1);
        int p = (c & ~15) | ((c ^ r) & 15);
        *(ulonglong2*)(Bs + r * KT + p * 8) =
            *(const ulonglong2*)(Btz + (size_t)(bn + r) * KT + c * 8);
    }
    __syncthreads();

    f32x4 zero = {0.f, 0.f, 0.f, 0.f};
    f32x4 acc[2][4];
    #pragma unroll
    for (int i = 0; i < 2; ++i)
        #pragma unroll
        for (int j = 0; j < 4; ++j) acc[i][j] = zero;

    #pragma unroll
    for (int ks = 0; ks < KT / 32; ++ks) {
        int c_lin = ks * 4 + (l >> 4);
        bf16x8 a[2], bfr[4];
        #pragma unroll
        for (int i = 0; i < 2; ++i) {
            int m = rw + i * 16 + (l & 15);
            int p = (c_lin & ~15) | ((c_lin ^ m) & 15);
            a[i] = *(const bf16x8*)(As + m * KT + p * 8);
        }
        #pragma unroll
        for (int j = 0; j < 4; ++j) {
            int n = cw + j * 16 + (l & 15);
            int p = (c_lin & ~15) | ((c_lin ^ n) & 15);
            bfr[j] = *(const bf16x8*)(Bs + n * KT + p * 8);
        }
        #pragma unroll
        for (int i = 0; i < 2; ++i)
            #pragma unroll
            for (int j = 0; j < 4; ++j)
                acc[i][j] = __builtin_amdgcn_mfma_f32_16x16x32_bf16(a[i], bfr[j], acc[i][j], 0, 0, 0);
    }

    #pragma unroll
    for (int i = 0; i < 2; ++i) {
        int rowbase = bm + rw + i * 16 + (l >> 4) * 4;
        #pragma unroll
        for (int j = 0; j < 4; ++j) {
            int col = bn + cw + j * 16 + (l & 15);
            float v[4];
            #pragma unroll
            for (int reg = 0; reg < 4; ++reg) v[reg] = acc[i][j][reg] + biasz[col];
            if (epi == 2) {
                #pragma unroll
                for (int reg = 0; reg < 4; ++reg)
                    ((float*)Cv)[(size_t)(rowbase + reg) * N + col] =
                        v[reg] + res[(size_t)(rowbase + reg) * N + col];
            } else if (epi == 6) {
                #pragma unroll
                for (int reg = 0; reg < 4; ++reg)
                    ((unsigned short*)Cv)[(size_t)(rowbase + reg) * N + col] = f2b(gelu_exact(v[reg]));
            } else if (epi == 8) {
                int bb = rowbase >> 12, s = rowbase & 4095;
                float4 o;
                o.x = gelu_exact(v[0]) + res[(size_t)(rowbase + 0) * N + col];
                o.y = gelu_exact(v[1]) + res[(size_t)(rowbase + 1) * N + col];
                o.z = gelu_exact(v[2]) + res[(size_t)(rowbase + 2) * N + col];
                o.w = gelu_exact(v[3]) + res[(size_t)(rowbase + 3) * N + col];
                *(float4*)(((float*)Cv) + ((size_t)(bb * 128 + col)) * 4096 + s) = o;
            } else { // epi == 7
                if (z < 2) {
                    unsigned short* dst = ((unsigned short*)Cv) + (size_t)z * MTOT * 128;
                    #pragma unroll
                    for (int reg = 0; reg < 4; ++reg)
                        dst[(size_t)(rowbase + reg) * 128 + col] = f2b(v[reg]);
                } else {
                    // V pre-swizzled image: chunk = (bb*64 + s/64), 8192 elems each.
                    // offset = c*64 + ((g ^ (c&7))*8) + (s&7), g = (s>>3)&7.
                    int bb = rowbase >> 12, s = rowbase & 4095;
                    int kc = s >> 6, g = (s >> 3) & 7;
                    ushort4 o;
                    o.x = f2b(v[0]); o.y = f2b(v[1]); o.z = f2b(v[2]); o.w = f2b(v[3]);
                    *(ushort4*)(((unsigned short*)Cv) + (size_t)2 * MTOT * 128 +
                                (((size_t)bb * 64 + kc) << 13) +
                                col * 64 + ((g ^ (col & 7)) << 3) + (s & 7)) = o;
                }
            }
        }
    }
}

// ---------------- Pass 1: QK^T via MFMA -> P = exp2(sv) bf16 store + fused column sums ----------------
__global__ __launch_bounds__(256) void scores_p(
    const unsigned short* __restrict__ qh, const unsigned short* __restrict__ kh,
    unsigned short* __restrict__ P_all, float* __restrict__ psum_all)
{
    __shared__ unsigned short Qs[128 * 128];
    __shared__ unsigned short Ks[128 * 128];
    __shared__ float csum[2][128];
    const int b = blockIdx.z;
    const unsigned short* Q = qh + (size_t)b * S * 128;
    const unsigned short* Km = kh + (size_t)b * S * 128;
    unsigned short* P = P_all + (size_t)b * S * S;
    const int bm = blockIdx.y * 128;
    const int bn = blockIdx.x * 128;
    const int tid = threadIdx.x;
    const int w = tid >> 6, l = tid & 63;
    const int wr = (w >> 1) * 64, wc = (w & 1) * 64;

    #pragma unroll
    for (int i = 0; i < 8; ++i) {
        int cid = i * 256 + tid;
        int r = cid >> 4, c = cid & 15;
        int p = c ^ (r & 15);
        *(ulonglong2*)(Qs + r * 128 + p * 8) =
            *(const ulonglong2*)(Q + (size_t)(bm + r) * 128 + c * 8);
        *(ulonglong2*)(Ks + r * 128 + p * 8) =
            *(const ulonglong2*)(Km + (size_t)(bn + r) * 128 + c * 8);
    }
    __syncthreads();

    f32x4 zero = {0.f, 0.f, 0.f, 0.f};
    f32x4 acc[4][4];
    #pragma unroll
    for (int i = 0; i < 4; ++i)
        #pragma unroll
        for (int j = 0; j < 4; ++j) acc[i][j] = zero;

    #pragma unroll
    for (int ks = 0; ks < 4; ++ks) {
        bf16x8 a[4], bfr[4];
        #pragma unroll
        for (int i = 0; i < 4; ++i) {
            int m = wr + i * 16 + (l & 15);
            int p = (ks * 4 + (l >> 4)) ^ (m & 15);
            a[i] = *(const bf16x8*)(Qs + m * 128 + p * 8);
        }
        #pragma unroll
        for (int j = 0; j < 4; ++j) {
            int n = wc + j * 16 + (l & 15);
            int p = (ks * 4 + (l >> 4)) ^ (n & 15);
            bfr[j] = *(const bf16x8*)(Ks + n * 128 + p * 8);
        }
        #pragma unroll
        for (int i = 0; i < 4; ++i)
            #pragma unroll
            for (int j = 0; j < 4; ++j)
                acc[i][j] = __builtin_amdgcn_mfma_f32_16x16x32_bf16(a[i], bfr[j], acc[i][j], 0, 0, 0);
    }

    // epilogue: P = exp2(sv), store bf16, accumulate column sums of rounded values
    float jsum[4];
    #pragma unroll
    for (int j = 0; j < 4; ++j) jsum[j] = 0.f;
    #pragma unroll
    for (int i = 0; i < 4; ++i) {
        #pragma unroll
        for (int j = 0; j < 4; ++j) {
            int col = bn + wc + j * 16 + (l & 15);
            #pragma unroll
            for (int reg = 0; reg < 4; ++reg) {
                int row = bm + wr + i * 16 + (l >> 4) * 4 + reg;
                unsigned short h = f2b_ru(exp2f(acc[i][j][reg] * SCLOG2E));
                P[(size_t)row * S + col] = h;
                jsum[j] += b2f(h);
            }
        }
    }
    #pragma unroll
    for (int j = 0; j < 4; ++j) {
        jsum[j] += __shfl_xor(jsum[j], 16);
        jsum[j] += __shfl_xor(jsum[j], 32);
    }
    if (l < 16) {
        #pragma unroll
        for (int j = 0; j < 4; ++j)
            csum[w >> 1][wc + j * 16 + l] = jsum[j];
    }
    __syncthreads();
    if (tid < 128) {
        float s = csum[0][tid] + csum[1][tid];
        psum_all[((size_t)(b * 32 + blockIdx.y)) * S + bn + tid] = s;
    }
}

// ---------------- merge 32 per-tile column-sum partials -> rl = 1/l ----------------
__global__ __launch_bounds__(256) void colfin(
    const float* __restrict__ psum_all, float* __restrict__ rl_all)
{
    const int b = blockIdx.y;
    int col = blockIdx.x * 256 + threadIdx.x;
    float L = 0.f;
    #pragma unroll
    for (int t = 0; t < 32; ++t)
        L += psum_all[((size_t)(b * 32 + t)) * S + col];
    rl_all[(size_t)b * S + col] = 1.0f / L;
}

// ---------------- fold 1/l into V image (in place, bf16); k recovered from swizzled offset ----------------
__global__ __launch_bounds__(256) void vscale(
    unsigned short* __restrict__ Vimg_all, const float* __restrict__ rl_all)
{
    const int b = blockIdx.z;
    unsigned short* Vimg = Vimg_all + (size_t)b * CNUM * S;
    const float* rl = rl_all + (size_t)b * S;
    int i = (blockIdx.x * 256 + threadIdx.x) * 4;   // elem offset within batch image
    int kc = i >> 13;
    int off = i & 8191;
    int c = off >> 6;
    int p = (off >> 3) & 7;
    int g = p ^ (c & 7);
    int k = kc * 64 + g * 8 + (off & 7);
    ushort4 v = *(ushort4*)(Vimg + i);
    float4 r = *(const float4*)(rl + k);
    v.x = f2b(b2f(v.x) * r.x);
    v.y = f2b(b2f(v.y) * r.y);
    v.z = f2b(b2f(v.z) * r.z);
    v.w = f2b(b2f(v.w) * r.w);
    *(ushort4*)(Vimg + i) = v;
}

// ---------------- Pass 2: attout = P @ V̂t — async pipelined ----------------
// grid (NSPLIT, S/128, BATCH). V̂ arrives as pre-swizzled 16 KB/64-k images; staged via
// global_load_lds into a double buffer (T3/T4: counted vmcnt(4) before each raw s_barrier,
// NEVER a vmcnt(0) drain in the loop). P register pipeline (depth 1) now has a full
// uninterrupted iteration of hiding window and survives across barriers.
__global__ __launch_bounds__(256, 4) void attnv_async(
    const unsigned short* __restrict__ P_all, const unsigned short* __restrict__ Vimg_all,
    unsigned short* __restrict__ parts)
{
    __shared__ unsigned short Vs[2][128 * KCH2];   // 2 x 16 KB
    const int b = blockIdx.z;
    const unsigned short* P = P_all + (size_t)b * S * S;
    const unsigned short* Vimg = Vimg_all + (((size_t)b * 64) << 13);  // b * CNUM * S
    unsigned short* Pout = parts + (size_t)blockIdx.x * ((size_t)MTOT * CNUM)
                                 + (size_t)b * S * CNUM;
    const int bq = blockIdx.y * 128;
    const int kc0 = blockIdx.x * (S / NSPLIT / KCH2);   // first V chunk (x*8)
    const int tid = threadIdx.x;
    const int w = tid >> 6, l = tid & 63;
    const int lm = l & 15, lq = l >> 4;
    const int row0 = bq + w * 32;

    f32x4 zero = {0.f, 0.f, 0.f, 0.f};
    f32x4 acc[2][8];
    #pragma unroll
    for (int i = 0; i < 2; ++i)
        #pragma unroll
        for (int j = 0; j < 8; ++j) acc[i][j] = zero;

    const unsigned short* p0 = P + (size_t)(row0 + lm) * S;
    const unsigned short* p1 = P + (size_t)(row0 + 16 + lm) * S;
    const int kO = kc0 * KCH2 + lq * 8;

    // prologue: stage chunk 0 -> buf0 (oldest VMEM), then P prefetch for iter 0
    {
        const unsigned short* src = Vimg + ((size_t)kc0 << 13) + tid * 8;
        #pragma unroll
        for (int i = 0; i < 4; ++i)
            gl_lds16(src + i * 2048, &Vs[0][(i * 256 + tid) * 8]);
    }
    bf16x8 a00 = *(const bf16x8*)(p0 + kO);
    bf16x8 a01 = *(const bf16x8*)(p0 + kO + 32);
    bf16x8 a10 = *(const bf16x8*)(p1 + kO);
    bf16x8 a11 = *(const bf16x8*)(p1 + kO + 32);
    asm volatile("s_waitcnt vmcnt(4)" ::: "memory");   // own V0 landed; P0 stays in flight
    __builtin_amdgcn_s_barrier();
    asm volatile("" ::: "memory");

    #pragma unroll
    for (int ksg = 0; ksg < 8; ++ksg) {
        // issue next V stage (async DMA into the buffer freed by the last barrier)
        if (ksg < 7) {
            const unsigned short* src = Vimg + ((size_t)(kc0 + ksg + 1) << 13) + tid * 8;
            #pragma unroll
            for (int i = 0; i < 4; ++i)
                gl_lds16(src + i * 2048, &Vs[(ksg + 1) & 1][(i * 256 + tid) * 8]);
        }
        // issue next P prefetch
        bf16x8 n00, n01, n10, n11;
        if (ksg < 7) {
            int kn = kO + (ksg + 1) * 64;
            n00 = *(const bf16x8*)(p0 + kn);
            n01 = *(const bf16x8*)(p0 + kn + 32);
            n10 = *(const bf16x8*)(p1 + kn);
            n11 = *(const bf16x8*)(p1 + kn + 32);
        }
        const unsigned short* vb = Vs[ksg & 1];
        #pragma unroll
        for (int j = 0; j < 8; ++j) {
            int n = j * 16 + lm;
            bf16x8 bv0 = *(const bf16x8*)(vb + n * 64 + ((lq ^ (n & 7)) << 3));
            bf16x8 bv1 = *(const bf16x8*)(vb + n * 64 + (((lq + 4) ^ (n & 7)) << 3));
            acc[0][j] = __builtin_amdgcn_mfma_f32_16x16x32_bf16(a00, bv0, acc[0][j], 0, 0, 0);
            acc[0][j] = __builtin_amdgcn_mfma_f32_16x16x32_bf16(a01, bv1, acc[0][j], 0, 0, 0);
            acc[1][j] = __builtin_amdgcn_mfma_f32_16x16x32_bf16(a10, bv0, acc[1][j], 0, 0, 0);
            acc[1][j] = __builtin_amdgcn_mfma_f32_16x16x32_bf16(a11, bv1, acc[1][j], 0, 0, 0);
        }
        if (ksg < 7) {
            a00 = n00; a01 = n01; a10 = n10; a11 = n11;
            // own next-V landed (counted: next-P's 4 loads stay in flight across the barrier)
            asm volatile("s_waitcnt vmcnt(4)" ::: "memory");
            __builtin_amdgcn_s_barrier();
            asm volatile("" ::: "memory");
        }
    }

    #pragma unroll
    for (int i = 0; i < 2; ++i) {
        int rowb = row0 + i * 16 + lq * 4;
        #pragma unroll
        for (int j = 0; j < 8; ++j) {
            int col = j * 16 + lm;
            #pragma unroll
            for (int reg = 0; reg < 4; ++reg)
                Pout[(size_t)(rowb + reg) * CNUM + col] = f2b(acc[i][j][reg]);
        }
    }
}

// ---------------- reduce NSPLIT bf16 partials -> bf16 attouth ----------------
__global__ __launch_bounds__(256) void reduce8b(
    const ushort4* __restrict__ parts, ushort4* __restrict__ dst)
{
    size_t i = (size_t)blockIdx.x * 256 + threadIdx.x;
    const size_t stride = (size_t)MTOT * CNUM / 4;
    float sx = 0.f, sy = 0.f, sz = 0.f, sw = 0.f;
    #pragma unroll
    for (int p = 0; p < NSPLIT; ++p) {
        ushort4 v = parts[i + p * stride];
        sx += b2f(v.x); sy += b2f(v.y); sz += b2f(v.z); sw += b2f(v.w);
    }
    ushort4 o;
    o.x = f2b(sx); o.y = f2b(sy); o.z = f2b(sz); o.w = f2b(sw);
    dst[i] = o;
}

// ---------------- LayerNorm rows -> bf16 ----------------
__global__ __launch_bounds__(256) void ln_rows(
    const float* __restrict__ y, const float* __restrict__ w, const float* __restrict__ bb,
    unsigned short* __restrict__ zh)
{
    int row = blockIdx.x * 4 + (threadIdx.x >> 6);
    int lane = threadIdx.x & 63;
    const float* yr = y + (size_t)row * CNUM;
    float v0 = yr[lane], v1 = yr[lane + 64];
    float sum = v0 + v1, sq = v0 * v0 + v1 * v1;
    #pragma unroll
    for (int off = 32; off; off >>= 1) {
        sum += __shfl_xor(sum, off);
        sq  += __shfl_xor(sq, off);
    }
    float mean = sum * (1.f / 128.f);
    float var = sq * (1.f / 128.f) - mean * mean;
    float r = rsqrtf(var + EPSLN);
    zh[(size_t)row * CNUM + lane]      = f2b((v0 - mean) * r * w[lane] + bb[lane]);
    zh[(size_t)row * CNUM + lane + 64] = f2b((v1 - mean) * r * w[lane + 64] + bb[lane + 64]);
}

extern "C" void kernel_launch(void* const* d_in, const int* in_sizes, int n_in,
                              void* d_out, int out_size, void* d_ws, size_t ws_size,
                              hipStream_t stream)
{
    (void)in_sizes; (void)n_in; (void)out_size; (void)ws_size;
    const float* x    = (const float*)d_in[0];
    const float* ln1w = (const float*)d_in[1];
    const float* ln1b = (const float*)d_in[2];
    const float* wq   = (const float*)d_in[3];
    const float* bq   = (const float*)d_in[4];
    const float* wk   = (const float*)d_in[5];
    const float* bk   = (const float*)d_in[6];
    const float* wv   = (const float*)d_in[7];
    const float* bv   = (const float*)d_in[8];
    const float* wo   = (const float*)d_in[9];
    const float* bo   = (const float*)d_in[10];
    const float* ln2w = (const float*)d_in[11];
    const float* ln2b = (const float*)d_in[12];
    const float* w1   = (const float*)d_in[13];
    const float* b1   = (const float*)d_in[14];
    const float* w2   = (const float*)d_in[15];
    const float* b2   = (const float*)d_in[16];
    float* out = (float*)d_out;

    float* ws = (float*)d_ws;
    const size_t NSC = (size_t)MTOT * CNUM;            // 2,097,152
    float* t      = ws;
    float* y      = t + NSC;
    float* psum   = y + NSC;                           // [B][32][S]
    float* rlc    = psum + (size_t)BATCH * 32 * S;
    unsigned short* parts = (unsigned short*)(rlc + (size_t)BATCH * S); // [NSPLIT][B][S][C] bf16, 32MB
    unsigned short* Pmat = parts + (size_t)NSPLIT * NSC;                // [B][S][S] bf16, 128MB
    unsigned short* xlh = Pmat + (size_t)BATCH * S * S;
    unsigned short* qh  = xlh + NSC;
    unsigned short* kh  = qh + NSC;                    // Vt must follow kh (epi 7 contiguity)
    unsigned short* Vt  = kh + NSC;                    // now holds the pre-swizzled V image
    unsigned short* attouth = Vt + NSC;
    unsigned short* zh  = attouth + NSC;
    unsigned short* hh  = zh + NSC;                    // [M,256] bf16
    unsigned short* wqkvh = hh + (size_t)MTOT * 256;
    unsigned short* woh = wqkvh + 3 * 16384;
    unsigned short* w1h = woh + 16384;                 // [256][128]
    unsigned short* w2h = w1h + 32768;                 // [128][256]
    float* bqkv = (float*)(w2h + 32768);               // [384]

    ln1_transpose<<<dim3(S / 64, BATCH), 256, 0, stream>>>(x, ln1w, ln1b, xlh, t);
    convw<<<dim3(128, 7), 256, 0, stream>>>(wq, wk, wv, wo, w1, w2, bq, bk, bv,
                                            wqkvh, woh, w1h, w2h, bqkv);

    // QKV: one launch, z = {q, k, v(image)}
    gemm_mfma<128><<<dim3(1, MTOT / 64, 3), 256, 0, stream>>>(
        xlh, wqkvh, bqkv, nullptr, qh, 128, 7);

    scores_p<<<dim3(S / 128, S / 128, BATCH), 256, 0, stream>>>(qh, kh, Pmat, psum);
    colfin<<<dim3(S / 256, BATCH), 256, 0, stream>>>(psum, rlc);
    vscale<<<dim3(CNUM * S / 4 / 256, 1, BATCH), 256, 0, stream>>>(Vt, rlc);
    attnv_async<<<dim3(NSPLIT, S / 128, BATCH), 256, 0, stream>>>(Pmat, Vt, parts);
    reduce8b<<<NSC / 4 / 256, 256, 0, stream>>>((const ushort4*)parts, (ushort4*)attouth);

    // y = attouth @ wo + bo + t
    gemm_mfma<128><<<dim3(1, MTOT / 64), 256, 0, stream>>>(attouth, woh, bo, t, y, 128, 2);
    ln_rows<<<MTOT / 4, 256, 0, stream>>>(y, ln2w, ln2b, zh);
    // hh = gelu(zh @ w1 + b1) -> bf16
    gemm_mfma<128><<<dim3(2, MTOT / 64), 256, 0, stream>>>(zh, w1h, b1, nullptr, hh, 256, 6);
    // out[b][c][s] = gelu(hh @ w2 + b2) + y   (fused transpose)
    gemm_mfma<256><<<dim3(1, MTOT / 64), 256, 0, stream>>>(hh, w2h, b2, y, out, 128, 8);
}

// Round 3
// 244.653 us; speedup vs baseline: 1.0389x; 1.0389x over previous
//
#include <hip/hip_runtime.h>
#include <math.h>

#define S 4096
#define CNUM 128
#define BATCH 4
#define MTOT (BATCH * S)
#define SCLOG2E 0.36067376022224085f   // 0.25 * log2(e): scores in log2 domain
#define EPSLN 1e-5f
#define KSPLIT 4                        // k-range split for fused attn partials
#define QSPLIT 4                        // q-range split for column-sum pass

typedef __attribute__((ext_vector_type(8))) short bf16x8;
typedef __attribute__((ext_vector_type(4))) float f32x4;

__device__ __forceinline__ float gelu_exact(float x) {
    return 0.5f * x * (1.0f + erff(x * 0.7071067811865476f));
}

__device__ __forceinline__ unsigned short f2b(float f) {
    union { float f; unsigned int u; } v; v.f = f;
    unsigned int r = (v.u + 0x7FFFu + ((v.u >> 16) & 1u)) >> 16;
    return (unsigned short)r;
}
// cheap round-half-up for positive values (2 ops)
__device__ __forceinline__ unsigned short f2b_ru(float f) {
    return (unsigned short)((__float_as_uint(f) + 0x8000u) >> 16);
}
__device__ __forceinline__ float b2f(unsigned short u) {
    return __uint_as_float((unsigned)u << 16);
}

// async 16B global->LDS (direct DMA, no VGPR round trip)
__device__ __forceinline__ void gl_lds16(const void* g, void* l) {
    __builtin_amdgcn_global_load_lds(
        (__attribute__((address_space(1))) void*)g,
        (__attribute__((address_space(3))) void*)l, 16, 0, 0);
}

// ---------------- transpose [B,C,S] -> [B,S,C]: t fp32 (residual), xlh bf16 (LN1 out) ----------------
__global__ __launch_bounds__(256) void ln1_transpose(
    const float* __restrict__ x, const float* __restrict__ w, const float* __restrict__ bb,
    unsigned short* __restrict__ xlh, float* __restrict__ t)
{
    __shared__ float tile[128][65];
    __shared__ float mu[64], rs[64];
    const int b = blockIdx.y;
    const int s0 = blockIdx.x * 64;
    const float* xb = x + (size_t)b * CNUM * S;
    for (int i = threadIdx.x; i < 128 * 64; i += 256) {
        int c = i >> 6, sl = i & 63;
        tile[c][sl] = xb[(size_t)c * S + s0 + sl];
    }
    __syncthreads();
    if (threadIdx.x < 64) {
        float sum = 0.f, sq = 0.f;
        for (int c = 0; c < 128; ++c) {
            float v = tile[c][threadIdx.x];
            sum += v; sq += v * v;
        }
        float m = sum * (1.f / 128.f);
        float var = sq * (1.f / 128.f) - m * m;
        mu[threadIdx.x] = m;
        rs[threadIdx.x] = rsqrtf(var + EPSLN);
    }
    __syncthreads();
    for (int i = threadIdx.x; i < 128 * 64; i += 256) {
        int c = i & 127, sl = i >> 7;
        float v = tile[c][sl];
        size_t idx = ((size_t)b * S + s0 + sl) * CNUM + c;
        t[idx] = v;
        xlh[idx] = f2b((v - mu[sl]) * rs[sl] * w[c] + bb[c]);
    }
}

// ---------------- weight convert+transpose fp32[K,N] -> bf16[N,K]; biases packed ----------------
__global__ __launch_bounds__(256) void convw(
    const float* __restrict__ wq, const float* __restrict__ wk, const float* __restrict__ wv,
    const float* __restrict__ wo, const float* __restrict__ w1, const float* __restrict__ w2,
    const float* __restrict__ bq, const float* __restrict__ bk, const float* __restrict__ bv,
    unsigned short* __restrict__ wqkvh, unsigned short* __restrict__ woh,
    unsigned short* __restrict__ w1h, unsigned short* __restrict__ w2h,
    float* __restrict__ bqkv)
{
    int a = blockIdx.y;
    int idx = blockIdx.x * 256 + threadIdx.x;
    if (a == 6) {
        if (idx < 128) bqkv[idx] = bq[idx];
        else if (idx < 256) bqkv[idx] = bk[idx - 128];
        else if (idx < 384) bqkv[idx] = bv[idx - 256];
        return;
    }
    const float* src; unsigned short* dst; int Nsh, Ksz;
    switch (a) {
        case 0: src = wq; dst = wqkvh;          Nsh = 7; Ksz = 128; break;
        case 1: src = wk; dst = wqkvh + 16384;  Nsh = 7; Ksz = 128; break;
        case 2: src = wv; dst = wqkvh + 32768;  Nsh = 7; Ksz = 128; break;
        case 3: src = wo; dst = woh;            Nsh = 7; Ksz = 128; break;
        case 4: src = w1; dst = w1h;            Nsh = 8; Ksz = 128; break;
        default: src = w2; dst = w2h;           Nsh = 7; Ksz = 256; break;
    }
    int total = Ksz << Nsh;
    if (idx >= total) return;
    int k = idx >> Nsh, n = idx & ((1 << Nsh) - 1);
    dst[n * Ksz + k] = f2b(src[idx]);
}

// ---------------- MFMA GEMM: C = A[M,KT](bf16) @ Bt[N,KT]^T(bf16) + bias, epilogues ----------------
// epi: 2 = fp32 +res -> C[M,N]
//      6 = gelu -> bf16 C[M,N]
//      7 = QKV combined (z=0,1: bf16 [M,128]; z=2: bf16 V written in pre-swizzled
//          per-64k-chunk LDS-image layout [b][kc][c*64 + ((g^(c&7))*8) + (k&7)])
//      8 = gelu + res -> fp32 out[b][col][s] (fused final transpose)
template<int KT>
__global__ __launch_bounds__(256) void gemm_mfma(
    const unsigned short* __restrict__ A, const unsigned short* __restrict__ Bt,
    const float* __restrict__ bias, const float* __restrict__ res,
    void* __restrict__ Cv, int N, int epi)
{
    constexpr int CH = KT / 8;
    constexpr int CSH = (KT == 128) ? 4 : 5;
    __shared__ unsigned short As[64 * KT];
    __shared__ unsigned short Bs[128 * KT];
    const int bm = blockIdx.y * 64;
    const int bn = blockIdx.x * 128;
    const int z = blockIdx.z;
    const unsigned short* Btz = (epi == 7) ? Bt + z * 16384 : Bt;
    const float* biasz = (epi == 7) ? bias + z * 128 : bias;
    const int tid = threadIdx.x;
    const int w = tid >> 6, l = tid & 63;
    const int rw = (w & 1) * 32, cw = (w >> 1) * 64;

    #pragma unroll
    for (int i = 0; i < (64 * CH) / 256; ++i) {
        int cid = i * 256 + tid;
        int r = cid >> CSH, c = cid & (CH - 1);
        int p = (c & ~15) | ((c ^ r) & 15);
        *(ulonglong2*)(As + r * KT + p * 8) =
            *(const ulonglong2*)(A + (size_t)(bm + r) * KT + c * 8);
    }
    #pragma unroll
    for (int i = 0; i < (128 * CH) / 256; ++i) {
        int cid = i * 256 + tid;
        int r = cid >> CSH, c = cid & (CH - 1);
        int p = (c & ~15) | ((c ^ r) & 15);
        *(ulonglong2*)(Bs + r * KT + p * 8) =
            *(const ulonglong2*)(Btz + (size_t)(bn + r) * KT + c * 8);
    }
    __syncthreads();

    f32x4 zero = {0.f, 0.f, 0.f, 0.f};
    f32x4 acc[2][4];
    #pragma unroll
    for (int i = 0; i < 2; ++i)
        #pragma unroll
        for (int j = 0; j < 4; ++j) acc[i][j] = zero;

    #pragma unroll
    for (int ks = 0; ks < KT / 32; ++ks) {
        int c_lin = ks * 4 + (l >> 4);
        bf16x8 a[2], bfr[4];
        #pragma unroll
        for (int i = 0; i < 2; ++i) {
            int m = rw + i * 16 + (l & 15);
            int p = (c_lin & ~15) | ((c_lin ^ m) & 15);
            a[i] = *(const bf16x8*)(As + m * KT + p * 8);
        }
        #pragma unroll
        for (int j = 0; j < 4; ++j) {
            int n = cw + j * 16 + (l & 15);
            int p = (c_lin & ~15) | ((c_lin ^ n) & 15);
            bfr[j] = *(const bf16x8*)(Bs + n * KT + p * 8);
        }
        #pragma unroll
        for (int i = 0; i < 2; ++i)
            #pragma unroll
            for (int j = 0; j < 4; ++j)
                acc[i][j] = __builtin_amdgcn_mfma_f32_16x16x32_bf16(a[i], bfr[j], acc[i][j], 0, 0, 0);
    }

    #pragma unroll
    for (int i = 0; i < 2; ++i) {
        int rowbase = bm + rw + i * 16 + (l >> 4) * 4;
        #pragma unroll
        for (int j = 0; j < 4; ++j) {
            int col = bn + cw + j * 16 + (l & 15);
            float v[4];
            #pragma unroll
            for (int reg = 0; reg < 4; ++reg) v[reg] = acc[i][j][reg] + biasz[col];
            if (epi == 2) {
                #pragma unroll
                for (int reg = 0; reg < 4; ++reg)
                    ((float*)Cv)[(size_t)(rowbase + reg) * N + col] =
                        v[reg] + res[(size_t)(rowbase + reg) * N + col];
            } else if (epi == 6) {
                #pragma unroll
                for (int reg = 0; reg < 4; ++reg)
                    ((unsigned short*)Cv)[(size_t)(rowbase + reg) * N + col] = f2b(gelu_exact(v[reg]));
            } else if (epi == 8) {
                int bb = rowbase >> 12, s = rowbase & 4095;
                float4 o;
                o.x = gelu_exact(v[0]) + res[(size_t)(rowbase + 0) * N + col];
                o.y = gelu_exact(v[1]) + res[(size_t)(rowbase + 1) * N + col];
                o.z = gelu_exact(v[2]) + res[(size_t)(rowbase + 2) * N + col];
                o.w = gelu_exact(v[3]) + res[(size_t)(rowbase + 3) * N + col];
                *(float4*)(((float*)Cv) + ((size_t)(bb * 128 + col)) * 4096 + s) = o;
            } else { // epi == 7
                if (z < 2) {
                    unsigned short* dst = ((unsigned short*)Cv) + (size_t)z * MTOT * 128;
                    #pragma unroll
                    for (int reg = 0; reg < 4; ++reg)
                        dst[(size_t)(rowbase + reg) * 128 + col] = f2b(v[reg]);
                } else {
                    // V pre-swizzled image: chunk = (bb*64 + s/64), 8192 elems each.
                    // offset = c*64 + ((g ^ (c&7))*8) + (s&7), g = (s>>3)&7.
                    int bb = rowbase >> 12, s = rowbase & 4095;
                    int kc = s >> 6, g = (s >> 3) & 7;
                    ushort4 o;
                    o.x = f2b(v[0]); o.y = f2b(v[1]); o.z = f2b(v[2]); o.w = f2b(v[3]);
                    *(ushort4*)(((unsigned short*)Cv) + (size_t)2 * MTOT * 128 +
                                (((size_t)bb * 64 + kc) << 13) +
                                col * 64 + ((g ^ (col & 7)) << 3) + (s & 7)) = o;
                }
            }
        }
    }
}

// ---------------- Pass A: column sums L[k] = sum_q f2b_ru(exp2(S[q,k])) — no P store ----------------
// grid (S/128 k-tiles, QSPLIT, BATCH). K-tile staged once; loop over q-tiles of this block's q-range.
__global__ __launch_bounds__(256) void colsum(
    const unsigned short* __restrict__ qh, const unsigned short* __restrict__ kh,
    float* __restrict__ psum_all)
{
    __shared__ unsigned short Qs[128 * 128];
    __shared__ unsigned short Ks[128 * 128];
    __shared__ float csum[2][128];
    const int b = blockIdx.z;
    const unsigned short* Q = qh + (size_t)b * S * 128;
    const unsigned short* Km = kh + (size_t)b * S * 128;
    const int bn = blockIdx.x * 128;
    const int q0 = blockIdx.y * (S / QSPLIT);
    const int tid = threadIdx.x;
    const int w = tid >> 6, l = tid & 63;
    const int wr = (w >> 1) * 64, wc = (w & 1) * 64;
    const int lm = l & 15, lq = l >> 4;

    // stage K tile once (swizzled, scores_p pattern)
    #pragma unroll
    for (int i = 0; i < 8; ++i) {
        int cid = i * 256 + tid;
        int r = cid >> 4, c = cid & 15;
        int p = c ^ (r & 15);
        *(ulonglong2*)(Ks + r * 128 + p * 8) =
            *(const ulonglong2*)(Km + (size_t)(bn + r) * 128 + c * 8);
    }

    float jsum[4] = {0.f, 0.f, 0.f, 0.f};
    for (int qt = 0; qt < (S / QSPLIT) / 128; ++qt) {
        __syncthreads();   // protect Qs from previous iteration's readers (also covers Ks stage on qt=0)
        #pragma unroll
        for (int i = 0; i < 8; ++i) {
            int cid = i * 256 + tid;
            int r = cid >> 4, c = cid & 15;
            int p = c ^ (r & 15);
            *(ulonglong2*)(Qs + r * 128 + p * 8) =
                *(const ulonglong2*)(Q + (size_t)(q0 + qt * 128 + r) * 128 + c * 8);
        }
        __syncthreads();

        f32x4 zero = {0.f, 0.f, 0.f, 0.f};
        f32x4 acc[4][4];
        #pragma unroll
        for (int i = 0; i < 4; ++i)
            #pragma unroll
            for (int j = 0; j < 4; ++j) acc[i][j] = zero;

        #pragma unroll
        for (int ks = 0; ks < 4; ++ks) {
            bf16x8 a[4], bfr[4];
            #pragma unroll
            for (int i = 0; i < 4; ++i) {
                int m = wr + i * 16 + lm;
                int p = (ks * 4 + lq) ^ (m & 15);
                a[i] = *(const bf16x8*)(Qs + m * 128 + p * 8);
            }
            #pragma unroll
            for (int j = 0; j < 4; ++j) {
                int n = wc + j * 16 + lm;
                int p = (ks * 4 + lq) ^ (n & 15);
                bfr[j] = *(const bf16x8*)(Ks + n * 128 + p * 8);
            }
            #pragma unroll
            for (int i = 0; i < 4; ++i)
                #pragma unroll
                for (int j = 0; j < 4; ++j)
                    acc[i][j] = __builtin_amdgcn_mfma_f32_16x16x32_bf16(a[i], bfr[j], acc[i][j], 0, 0, 0);
        }

        #pragma unroll
        for (int i = 0; i < 4; ++i)
            #pragma unroll
            for (int j = 0; j < 4; ++j)
                #pragma unroll
                for (int reg = 0; reg < 4; ++reg)
                    jsum[j] += b2f(f2b_ru(exp2f(acc[i][j][reg] * SCLOG2E)));
    }

    #pragma unroll
    for (int j = 0; j < 4; ++j) {
        jsum[j] += __shfl_xor(jsum[j], 16);
        jsum[j] += __shfl_xor(jsum[j], 32);
    }
    if (l < 16) {
        #pragma unroll
        for (int j = 0; j < 4; ++j)
            csum[w >> 1][wc + j * 16 + l] = jsum[j];
    }
    __syncthreads();
    if (tid < 128)
        psum_all[((size_t)(blockIdx.y * BATCH + b)) * S + bn + tid] = csum[0][tid] + csum[1][tid];
}

// ---------------- fold 1/L into V image (in place, bf16); k recovered from swizzled offset ----------------
__global__ __launch_bounds__(256) void vscale(
    unsigned short* __restrict__ Vimg_all, const float* __restrict__ psum_all)
{
    const int b = blockIdx.z;
    unsigned short* Vimg = Vimg_all + (size_t)b * CNUM * S;
    int i = (blockIdx.x * 256 + threadIdx.x) * 4;   // elem offset within batch image
    int kc = i >> 13;
    int off = i & 8191;
    int c = off >> 6;
    int p = (off >> 3) & 7;
    int g = p ^ (c & 7);
    int k = kc * 64 + g * 8 + (off & 7);
    float4 L = *(const float4*)(psum_all + (size_t)b * S + k);
    #pragma unroll
    for (int t = 1; t < QSPLIT; ++t) {
        float4 Lt = *(const float4*)(psum_all + ((size_t)(t * BATCH + b)) * S + k);
        L.x += Lt.x; L.y += Lt.y; L.z += Lt.z; L.w += Lt.w;
    }
    ushort4 v = *(ushort4*)(Vimg + i);
    v.x = f2b(b2f(v.x) / L.x);
    v.y = f2b(b2f(v.y) / L.y);
    v.z = f2b(b2f(v.z) / L.z);
    v.w = f2b(b2f(v.w) / L.w);
    *(ushort4*)(Vimg + i) = v;
}

// ---------------- fused attention: out_part = exp2(Q K^T) @ Vhat, k-split ----------------
// grid (KSPLIT, S/128, BATCH), 256 thr. Q held in registers for the whole kernel.
// Per 64-k tile: stage K (swizzled LDS) + Vhat (pre-swizzled image via DMA); QK^T; exp2 ->
// wave-private P LDS buffer (write-then-read within the wave, no barrier); PV accumulate.
__global__ __launch_bounds__(256, 2) void fused_attnv(
    const unsigned short* __restrict__ qh, const unsigned short* __restrict__ kh,
    const unsigned short* __restrict__ Vimg_all, unsigned short* __restrict__ parts)
{
    __shared__ unsigned short Ks[64 * 128];      // 16 KB, swizzled p = c ^ (r&15)
    __shared__ unsigned short Vls[128 * 64];     // 16 KB, image chunk (linear DMA)
    __shared__ unsigned short Ps[4][32 * 64];    // 16 KB, per-wave P [32 q][64 k]
    const int b = blockIdx.z;
    const unsigned short* Qm = qh + (size_t)b * S * 128;
    const unsigned short* Km = kh + (size_t)b * S * 128;
    const unsigned short* Vimg = Vimg_all + (((size_t)b * 64) << 13);
    unsigned short* Pout = parts + (size_t)blockIdx.x * ((size_t)MTOT * CNUM)
                                 + (size_t)b * S * CNUM;
    const int q0 = blockIdx.y * 128;
    const int kt0 = blockIdx.x * (S / KSPLIT / 64);
    const int tid = threadIdx.x;
    const int w = tid >> 6, l = tid & 63;
    const int lm = l & 15, lq = l >> 4;
    const int row0 = q0 + w * 32;
    unsigned short* Pw = Ps[w];

    // Q fragments, persistent across all k-tiles
    bf16x8 aq[2][4];
    #pragma unroll
    for (int i = 0; i < 2; ++i)
        #pragma unroll
        for (int ks = 0; ks < 4; ++ks)
            aq[i][ks] = *(const bf16x8*)(Qm + (size_t)(row0 + i * 16 + lm) * 128 + (ks * 4 + lq) * 8);

    f32x4 zero = {0.f, 0.f, 0.f, 0.f};
    f32x4 acco[2][8];
    #pragma unroll
    for (int i = 0; i < 2; ++i)
        #pragma unroll
        for (int j = 0; j < 8; ++j) acco[i][j] = zero;

    for (int kt = 0; kt < S / KSPLIT / 64; ++kt) {
        const int kb = (kt0 + kt) * 64;
        if (kt) __syncthreads();   // previous iteration's readers done
        // stage K tile [64][128] with read swizzle
        #pragma unroll
        for (int i = 0; i < 4; ++i) {
            int cid = i * 256 + tid;
            int r = cid >> 4, c = cid & 15;
            int p = c ^ (r & 15);
            *(ulonglong2*)(Ks + r * 128 + p * 8) =
                *(const ulonglong2*)(Km + (size_t)(kb + r) * 128 + c * 8);
        }
        // stage Vhat chunk (pre-swizzled image, linear DMA)
        {
            const unsigned short* src = Vimg + (((size_t)(kt0 + kt)) << 13) + tid * 8;
            #pragma unroll
            for (int i = 0; i < 4; ++i)
                gl_lds16(src + i * 2048, &Vls[(i * 256 + tid) * 8]);
        }
        __syncthreads();

        // QK^T -> accs[2][4]  (32 q-rows x 64 k-cols per wave)
        f32x4 accs[2][4];
        #pragma unroll
        for (int i = 0; i < 2; ++i)
            #pragma unroll
            for (int j = 0; j < 4; ++j) accs[i][j] = zero;
        #pragma unroll
        for (int ks = 0; ks < 4; ++ks) {
            bf16x8 bk_[4];
            #pragma unroll
            for (int j = 0; j < 4; ++j) {
                int n = j * 16 + lm;
                int p = (ks * 4 + lq) ^ (n & 15);
                bk_[j] = *(const bf16x8*)(Ks + n * 128 + p * 8);
            }
            #pragma unroll
            for (int i = 0; i < 2; ++i)
                #pragma unroll
                for (int j = 0; j < 4; ++j)
                    accs[i][j] = __builtin_amdgcn_mfma_f32_16x16x32_bf16(aq[i][ks], bk_[j], accs[i][j], 0, 0, 0);
        }

        // P = exp2 -> wave-private LDS [32][64], swizzle s8 = (prow ^ (prow>>3)) & 7
        #pragma unroll
        for (int i = 0; i < 2; ++i)
            #pragma unroll
            for (int j = 0; j < 4; ++j)
                #pragma unroll
                for (int reg = 0; reg < 4; ++reg) {
                    int prow = i * 16 + lq * 4 + reg;
                    int pcol = j * 16 + lm;
                    unsigned short h = f2b_ru(exp2f(accs[i][j][reg] * SCLOG2E));
                    int s8 = (prow ^ (prow >> 3)) & 7;
                    Pw[prow * 64 + (((pcol >> 3) ^ s8) << 3) + (pcol & 7)] = h;
                }
        // wave-local RAW through LDS: compiler orders via lgkmcnt (no barrier needed)

        // PV: acco += P @ Vhat
        #pragma unroll
        for (int ks = 0; ks < 2; ++ks) {
            bf16x8 ap[2];
            #pragma unroll
            for (int i = 0; i < 2; ++i) {
                int prow = i * 16 + lm;
                int s8 = (prow ^ (prow >> 3)) & 7;
                ap[i] = *(const bf16x8*)(Pw + prow * 64 + (((ks * 4 + lq) ^ s8) << 3));
            }
            #pragma unroll
            for (int j = 0; j < 8; ++j) {
                int n = j * 16 + lm;
                bf16x8 bv = *(const bf16x8*)(Vls + n * 64 + (((ks * 4 + lq) ^ (n & 7)) << 3));
                acco[0][j] = __builtin_amdgcn_mfma_f32_16x16x32_bf16(ap[0], bv, acco[0][j], 0, 0, 0);
                acco[1][j] = __builtin_amdgcn_mfma_f32_16x16x32_bf16(ap[1], bv, acco[1][j], 0, 0, 0);
            }
        }
    }

    #pragma unroll
    for (int i = 0; i < 2; ++i) {
        int rowb = row0 + i * 16 + lq * 4;
        #pragma unroll
        for (int j = 0; j < 8; ++j) {
            int col = j * 16 + lm;
            #pragma unroll
            for (int reg = 0; reg < 4; ++reg)
                Pout[(size_t)(rowb + reg) * CNUM + col] = f2b(acco[i][j][reg]);
        }
    }
}

// ---------------- reduce KSPLIT bf16 partials -> bf16 attouth ----------------
__global__ __launch_bounds__(256) void reduce8b(
    const ushort4* __restrict__ parts, ushort4* __restrict__ dst)
{
    size_t i = (size_t)blockIdx.x * 256 + threadIdx.x;
    const size_t stride = (size_t)MTOT * CNUM / 4;
    float sx = 0.f, sy = 0.f, sz = 0.f, sw = 0.f;
    #pragma unroll
    for (int p = 0; p < KSPLIT; ++p) {
        ushort4 v = parts[i + p * stride];
        sx += b2f(v.x); sy += b2f(v.y); sz += b2f(v.z); sw += b2f(v.w);
    }
    ushort4 o;
    o.x = f2b(sx); o.y = f2b(sy); o.z = f2b(sz); o.w = f2b(sw);
    dst[i] = o;
}

// ---------------- LayerNorm rows -> bf16 ----------------
__global__ __launch_bounds__(256) void ln_rows(
    const float* __restrict__ y, const float* __restrict__ w, const float* __restrict__ bb,
    unsigned short* __restrict__ zh)
{
    int row = blockIdx.x * 4 + (threadIdx.x >> 6);
    int lane = threadIdx.x & 63;
    const float* yr = y + (size_t)row * CNUM;
    float v0 = yr[lane], v1 = yr[lane + 64];
    float sum = v0 + v1, sq = v0 * v0 + v1 * v1;
    #pragma unroll
    for (int off = 32; off; off >>= 1) {
        sum += __shfl_xor(sum, off);
        sq  += __shfl_xor(sq, off);
    }
    float mean = sum * (1.f / 128.f);
    float var = sq * (1.f / 128.f) - mean * mean;
    float r = rsqrtf(var + EPSLN);
    zh[(size_t)row * CNUM + lane]      = f2b((v0 - mean) * r * w[lane] + bb[lane]);
    zh[(size_t)row * CNUM + lane + 64] = f2b((v1 - mean) * r * w[lane + 64] + bb[lane + 64]);
}

extern "C" void kernel_launch(void* const* d_in, const int* in_sizes, int n_in,
                              void* d_out, int out_size, void* d_ws, size_t ws_size,
                              hipStream_t stream)
{
    (void)in_sizes; (void)n_in; (void)out_size; (void)ws_size;
    const float* x    = (const float*)d_in[0];
    const float* ln1w = (const float*)d_in[1];
    const float* ln1b = (const float*)d_in[2];
    const float* wq   = (const float*)d_in[3];
    const float* bq   = (const float*)d_in[4];
    const float* wk   = (const float*)d_in[5];
    const float* bk   = (const float*)d_in[6];
    const float* wv   = (const float*)d_in[7];
    const float* bv   = (const float*)d_in[8];
    const float* wo   = (const float*)d_in[9];
    const float* bo   = (const float*)d_in[10];
    const float* ln2w = (const float*)d_in[11];
    const float* ln2b = (const float*)d_in[12];
    const float* w1   = (const float*)d_in[13];
    const float* b1   = (const float*)d_in[14];
    const float* w2   = (const float*)d_in[15];
    const float* b2   = (const float*)d_in[16];
    float* out = (float*)d_out;

    float* ws = (float*)d_ws;
    const size_t NSC = (size_t)MTOT * CNUM;            // 2,097,152
    float* t      = ws;
    float* y      = t + NSC;
    float* psum   = y + NSC;                           // [QSPLIT][B][S]
    unsigned short* parts = (unsigned short*)(psum + (size_t)QSPLIT * BATCH * S); // [KSPLIT][B][S][C]
    unsigned short* xlh = parts + (size_t)KSPLIT * NSC;
    unsigned short* qh  = xlh + NSC;
    unsigned short* kh  = qh + NSC;                    // Vt must follow kh (epi 7 contiguity)
    unsigned short* Vt  = kh + NSC;                    // pre-swizzled V image
    unsigned short* attouth = Vt + NSC;
    unsigned short* zh  = attouth + NSC;
    unsigned short* hh  = zh + NSC;                    // [M,256] bf16
    unsigned short* wqkvh = hh + (size_t)MTOT * 256;
    unsigned short* woh = wqkvh + 3 * 16384;
    unsigned short* w1h = woh + 16384;                 // [256][128]
    unsigned short* w2h = w1h + 32768;                 // [128][256]
    float* bqkv = (float*)(w2h + 32768);               // [384]

    ln1_transpose<<<dim3(S / 64, BATCH), 256, 0, stream>>>(x, ln1w, ln1b, xlh, t);
    convw<<<dim3(128, 7), 256, 0, stream>>>(wq, wk, wv, wo, w1, w2, bq, bk, bv,
                                            wqkvh, woh, w1h, w2h, bqkv);

    // QKV: one launch, z = {q, k, v(image)}
    gemm_mfma<128><<<dim3(1, MTOT / 64, 3), 256, 0, stream>>>(
        xlh, wqkvh, bqkv, nullptr, qh, 128, 7);

    colsum<<<dim3(S / 128, QSPLIT, BATCH), 256, 0, stream>>>(qh, kh, psum);
    vscale<<<dim3(CNUM * S / 4 / 256, 1, BATCH), 256, 0, stream>>>(Vt, psum);
    fused_attnv<<<dim3(KSPLIT, S / 128, BATCH), 256, 0, stream>>>(qh, kh, Vt, parts);
    reduce8b<<<NSC / 4 / 256, 256, 0, stream>>>((const ushort4*)parts, (ushort4*)attouth);

    // y = attouth @ wo + bo + t
    gemm_mfma<128><<<dim3(1, MTOT / 64), 256, 0, stream>>>(attouth, woh, bo, t, y, 128, 2);
    ln_rows<<<MTOT / 4, 256, 0, stream>>>(y, ln2w, ln2b, zh);
    // hh = gelu(zh @ w1 + b1) -> bf16
    gemm_mfma<128><<<dim3(2, MTOT / 64), 256, 0, stream>>>(zh, w1h, b1, nullptr, hh, 256, 6);
    // out[b][c][s] = gelu(hh @ w2 + b2) + y   (fused transpose)
    gemm_mfma<256><<<dim3(1, MTOT / 64), 256, 0, stream>>>(hh, w2h, b2, y, out, 128, 8);
}